// Round 1
// baseline (507.260 us; speedup 1.0000x reference)
//
#include <hip/hip_runtime.h>
#include <cstdint>
#include <cstddef>

typedef _Float16 f16;
typedef _Float16 f16x4 __attribute__((ext_vector_type(4)));
typedef _Float16 f16x8 __attribute__((ext_vector_type(8)));
typedef float f32x4 __attribute__((ext_vector_type(4)));

#define LRELU_SLOPE 0.2f

// ---------------- prep: x (f32) -> x_h (f16), padded rows zeroed ----------------
__global__ __launch_bounds__(256) void k_prep_xh(const float* __restrict__ x,
                                                 f16* __restrict__ xh,
                                                 int nvalid, int npad) {
  int total = npad * 192;  // 768/4 float4-chunks per row
  for (int idx = blockIdx.x * blockDim.x + threadIdx.x; idx < total;
       idx += gridDim.x * blockDim.x) {
    int row = idx / 192;
    f16x4 o;
    if (row < nvalid) {
      const float4 v = *(const float4*)(x + (size_t)idx * 4);
      o[0] = (f16)v.x; o[1] = (f16)v.y; o[2] = (f16)v.z; o[3] = (f16)v.w;
    } else {
      o[0] = (f16)0.f; o[1] = (f16)0.f; o[2] = (f16)0.f; o[3] = (f16)0.f;
    }
    *(f16x4*)(xh + (size_t)idx * 4) = o;
  }
}

// ---------------- W [768][768] f32 -> Wt [n][k] f16 (transposed) ----------------
__global__ __launch_bounds__(256) void k_transpose_w(const float* __restrict__ W,
                                                     f16* __restrict__ Wt) {
  __shared__ float tile[32][33];
  int bn = blockIdx.x * 32;   // output-row block (n)
  int bk = blockIdx.y * 32;   // input-row block (k)
  int tx = threadIdx.x & 31, ty = threadIdx.x >> 5;  // ty 0..7
  #pragma unroll
  for (int r = ty; r < 32; r += 8)
    tile[r][tx] = W[(size_t)(bk + r) * 768 + bn + tx];
  __syncthreads();
  #pragma unroll
  for (int r = ty; r < 32; r += 8)
    Wt[(size_t)(bn + r) * 768 + bk + tx] = (f16)tile[tx][r];
}

// ---------------- CSR build ----------------
__global__ void k_zero_ints(int* __restrict__ p, int n) {
  for (int i = blockIdx.x * blockDim.x + threadIdx.x; i < n;
       i += gridDim.x * blockDim.x) p[i] = 0;
}

__global__ void k_hist(const int* __restrict__ dst, int E, int* __restrict__ counts) {
  for (int e = blockIdx.x * blockDim.x + threadIdx.x; e < E;
       e += gridDim.x * blockDim.x) atomicAdd(&counts[dst[e]], 1);
}

// single-wave exclusive scan (no barriers; shfl only)
__global__ __launch_bounds__(64) void k_scan(const int* __restrict__ counts,
                                             int* __restrict__ starts,
                                             int* __restrict__ cursor, int n) {
  int lane = threadIdx.x;
  int carry = 0;
  for (int base = 0; base < n; base += 64) {
    int i = base + lane;
    int v = (i < n) ? counts[i] : 0;
    int s = v;
    #pragma unroll
    for (int off = 1; off < 64; off <<= 1) {
      int t = __shfl_up(s, off);
      if (lane >= off) s += t;
    }
    if (i < n) { int ex = carry + s - v; starts[i] = ex; cursor[i] = ex; }
    carry += __shfl(s, 63);
  }
  if (lane == 0) starts[n] = carry;
}

__global__ void k_fill(const int* __restrict__ src, const int* __restrict__ dst, int E,
                       int* __restrict__ cursor, int* __restrict__ src_sorted) {
  for (int e = blockIdx.x * blockDim.x + threadIdx.x; e < E;
       e += gridDim.x * blockDim.x) {
    int slot = atomicAdd(&cursor[dst[e]], 1);
    src_sorted[slot] = src[e];
  }
}

// ---------------- fp16 MFMA GEMM: C[M][768] = A[Mpad][768] * B(=Wt^T)[768][768] ----------------
// A: [Mpad][768] k-contiguous. Bt: [768 n-rows][768 k] k-contiguous. C stored f16.
__global__ __launch_bounds__(256) void k_gemm_f16(const f16* __restrict__ A,
                                                  const f16* __restrict__ Bt,
                                                  f16* __restrict__ C, int Mvalid) {
  // LDS layout [k4][row][8 halfs]: fragment ds_read_b128 conflict-free
  __shared__ __align__(16) f16 As[4][128][8];
  __shared__ __align__(16) f16 Bs[4][128][8];
  const int K = 768;
  const int tid = threadIdx.x;
  const int bm = blockIdx.x * 128;
  const int bn = blockIdx.y * 128;
  const int lane = tid & 63;
  const int wave = tid >> 6;
  const int wr = (wave >> 1) * 64;  // wave row offset in tile
  const int wc = (wave & 1) * 64;   // wave col offset
  const int ar = tid >> 2;          // staging row 0..63
  const int ak = tid & 3;           // staging k-chunk
  const f16* Ap = A + (size_t)(bm + ar) * K + ak * 8;
  const f16* Bp = Bt + (size_t)(bn + ar) * K + ak * 8;

  f32x4 acc[4][4];
  const f32x4 vzero = {0.f, 0.f, 0.f, 0.f};
  #pragma unroll
  for (int i = 0; i < 4; i++)
    #pragma unroll
    for (int j = 0; j < 4; j++) acc[i][j] = vzero;

  const int fr = lane & 15;  // fragment row/col within 16
  const int fq = lane >> 4;  // k-chunk selector / C-row quad

  for (int k0 = 0; k0 < K; k0 += 32) {
    *(f16x8*)(&As[ak][ar][0])      = *(const f16x8*)(Ap + k0);
    *(f16x8*)(&As[ak][ar + 64][0]) = *(const f16x8*)(Ap + (size_t)64 * K + k0);
    *(f16x8*)(&Bs[ak][ar][0])      = *(const f16x8*)(Bp + k0);
    *(f16x8*)(&Bs[ak][ar + 64][0]) = *(const f16x8*)(Bp + (size_t)64 * K + k0);
    __syncthreads();
    f16x8 af[4], bf[4];
    #pragma unroll
    for (int i = 0; i < 4; i++) af[i] = *(const f16x8*)(&As[fq][wr + i * 16 + fr][0]);
    #pragma unroll
    for (int j = 0; j < 4; j++) bf[j] = *(const f16x8*)(&Bs[fq][wc + j * 16 + fr][0]);
    #pragma unroll
    for (int i = 0; i < 4; i++)
      #pragma unroll
      for (int j = 0; j < 4; j++)
        acc[i][j] = __builtin_amdgcn_mfma_f32_16x16x32_f16(af[i], bf[j], acc[i][j], 0, 0, 0);
    __syncthreads();
  }

  // C/D layout (m89-verified): col = lane&15, row = (lane>>4)*4 + reg
  #pragma unroll
  for (int i = 0; i < 4; i++) {
    #pragma unroll
    for (int j = 0; j < 4; j++) {
      int col = bn + wc + j * 16 + fr;
      #pragma unroll
      for (int r = 0; r < 4; r++) {
        int row = bm + wr + i * 16 + fq * 4 + r;
        if (row < Mvalid) C[(size_t)row * 768 + col] = (f16)acc[i][j][r];
      }
    }
  }
}

// ---------------- attention logits: al[n][h] = sum_c h[n][h*C+c]*a[h][c] ----------------
template <int H>
__global__ __launch_bounds__(256) void k_al(const f16* __restrict__ h,
                                            const float* __restrict__ a_src,
                                            const float* __restrict__ a_dst,
                                            float* __restrict__ als,
                                            float* __restrict__ ald, int N) {
  int node = blockIdx.x * 4 + (threadIdx.x >> 6);
  int lane = threadIdx.x & 63;
  if (node >= N) return;
  const f16x4* hp = (const f16x4*)(h + (size_t)node * 768 + lane * 12);
  float ss = 0.f, sd = 0.f;
  int cbase = lane * 12;
  #pragma unroll
  for (int q = 0; q < 3; q++) {
    f16x4 hv = hp[q];
    #pragma unroll
    for (int j = 0; j < 4; j++) {
      int c = cbase + q * 4 + j;
      float v = (float)hv[j];
      ss += v * a_src[c];
      sd += v * a_dst[c];
    }
  }
  const int red = (H == 8) ? 8 : 64;  // H=8: head = 8-lane group
  #pragma unroll
  for (int off = 1; off < red; off <<= 1) {
    ss += __shfl_xor(ss, off);
    sd += __shfl_xor(sd, off);
  }
  if (H == 8) {
    if ((lane & 7) == 0) {
      als[(size_t)node * 8 + (lane >> 3)] = ss;
      ald[(size_t)node * 8 + (lane >> 3)] = sd;
    }
  } else {
    if (lane == 0) { als[node] = ss; ald[node] = sd; }
  }
}

// ---------------- fused segment softmax + aggregation + bias (+ELU) ----------------
template <int H, bool FINAL>
__global__ __launch_bounds__(256) void k_aggregate(
    const f16* __restrict__ h, const float* __restrict__ als,
    const float* __restrict__ ald, const int* __restrict__ starts,
    const int* __restrict__ src_sorted, const float* __restrict__ bias,
    void* __restrict__ outv, int nvalid) {
  int n = blockIdx.x;
  int t = threadIdx.x;
  if (n >= nvalid) {  // pad rows for layer-1 output (feeds GEMM2): zero
    if (!FINAL) {
      f16* o = (f16*)outv + (size_t)n * 768;
      o[t] = (f16)0.f; o[t + 256] = (f16)0.f; o[t + 512] = (f16)0.f;
    }
    return;
  }
  __shared__ float s_m[H];
  __shared__ float s_z[H];
  __shared__ int s_src[256];
  __shared__ float s_alpha[256 * H];
  int start = starts[n];
  int deg = starts[n + 1] - start;
  int wave = t >> 6, lane = t & 63;

  if (wave == 0) {  // segment max + denom on wave 0 (deg ~ 17)
    float aldv[H], lm[H], lz[H];
    #pragma unroll
    for (int hh = 0; hh < H; hh++) { aldv[hh] = ald[(size_t)n * H + hh]; lm[hh] = -1e30f; lz[hh] = 0.f; }
    for (int i = lane; i < deg; i += 64) {
      int s = src_sorted[start + i];
      #pragma unroll
      for (int hh = 0; hh < H; hh++) {
        float v = als[(size_t)s * H + hh] + aldv[hh];
        v = v > 0.f ? v : LRELU_SLOPE * v;
        lm[hh] = fmaxf(lm[hh], v);
      }
    }
    #pragma unroll
    for (int off = 1; off < 64; off <<= 1)
      #pragma unroll
      for (int hh = 0; hh < H; hh++) lm[hh] = fmaxf(lm[hh], __shfl_xor(lm[hh], off));
    for (int i = lane; i < deg; i += 64) {
      int s = src_sorted[start + i];
      #pragma unroll
      for (int hh = 0; hh < H; hh++) {
        float v = als[(size_t)s * H + hh] + aldv[hh];
        v = v > 0.f ? v : LRELU_SLOPE * v;
        lz[hh] += __expf(v - lm[hh]);
      }
    }
    #pragma unroll
    for (int off = 1; off < 64; off <<= 1)
      #pragma unroll
      for (int hh = 0; hh < H; hh++) lz[hh] += __shfl_xor(lz[hh], off);
    if (lane == 0) {
      #pragma unroll
      for (int hh = 0; hh < H; hh++) { s_m[hh] = lm[hh]; s_z[hh] = lz[hh] + 1e-16f; }
    }
  }
  __syncthreads();

  float acc0 = 0.f, acc1 = 0.f, acc2 = 0.f;
  const int h0 = (H == 8) ? (t / 96) : 0;
  const int h1 = (H == 8) ? ((t + 256) / 96) : 0;
  const int h2 = (H == 8) ? ((t + 512) / 96) : 0;

  for (int cb = 0; cb < deg; cb += 256) {
    int cnt = min(256, deg - cb);
    for (int idx = t; idx < cnt * H; idx += 256) {
      int e = idx / H, hh = idx - e * H;
      int s = src_sorted[start + cb + e];
      if (hh == 0) s_src[e] = s;
      float v = als[(size_t)s * H + hh] + ald[(size_t)n * H + hh];
      v = v > 0.f ? v : LRELU_SLOPE * v;
      s_alpha[e * H + hh] = __expf(v - s_m[hh]) / s_z[hh];
    }
    __syncthreads();
    for (int e = 0; e < cnt; e++) {
      const f16* hp = h + (size_t)s_src[e] * 768;
      const float* ap = &s_alpha[e * H];
      acc0 += ap[h0] * (float)hp[t];
      acc1 += ap[h1] * (float)hp[t + 256];
      acc2 += ap[h2] * (float)hp[t + 512];
    }
    __syncthreads();
  }

  float v0 = acc0 + bias[t];
  float v1 = acc1 + bias[t + 256];
  float v2 = acc2 + bias[t + 512];
  if (!FINAL) {
    v0 = v0 > 0.f ? v0 : expm1f(v0);
    v1 = v1 > 0.f ? v1 : expm1f(v1);
    v2 = v2 > 0.f ? v2 : expm1f(v2);
    f16* o = (f16*)outv + (size_t)n * 768;
    o[t] = (f16)v0; o[t + 256] = (f16)v1; o[t + 512] = (f16)v2;
  } else {
    float* o = (float*)outv + (size_t)n * 768;
    o[t] = v0; o[t + 256] = v1; o[t + 512] = v2;
  }
}

// ---------------- launcher ----------------
extern "C" void kernel_launch(void* const* d_in, const int* in_sizes, int n_in,
                              void* d_out, int out_size, void* d_ws, size_t ws_size,
                              hipStream_t stream) {
  const float* x   = (const float*)d_in[0];
  const int*   ei  = (const int*)d_in[1];
  const float* W1  = (const float*)d_in[2];
  const float* as1 = (const float*)d_in[3];
  const float* ad1 = (const float*)d_in[4];
  const float* b1  = (const float*)d_in[5];
  const float* W2  = (const float*)d_in[6];
  const float* as2 = (const float*)d_in[7];
  const float* ad2 = (const float*)d_in[8];
  const float* b2  = (const float*)d_in[9];

  const int N = in_sizes[0] / 768;
  const int E = in_sizes[1] / 2;
  const int Mpad = (N + 127) & ~127;
  const int* srcp = ei;
  const int* dstp = ei + E;

  char* p = (char*)d_ws;
  auto alloc = [&](size_t b) { char* r = p; p += (b + 255) & ~(size_t)255; return r; };
  f16*   bufX   = (f16*)alloc((size_t)Mpad * 768 * sizeof(f16));  // x_h, then out1
  f16*   bufH   = (f16*)alloc((size_t)Mpad * 768 * sizeof(f16));  // h1, then h2
  f16*   Wt1    = (f16*)alloc((size_t)768 * 768 * sizeof(f16));
  f16*   Wt2    = (f16*)alloc((size_t)768 * 768 * sizeof(f16));
  float* als1   = (float*)alloc((size_t)N * 8 * sizeof(float));
  float* ald1   = (float*)alloc((size_t)N * 8 * sizeof(float));
  float* als2   = (float*)alloc((size_t)N * sizeof(float));
  float* ald2   = (float*)alloc((size_t)N * sizeof(float));
  int*   counts = (int*)alloc((size_t)N * sizeof(int));
  int*   starts = (int*)alloc(((size_t)N + 1) * sizeof(int));
  int*   cursor = (int*)alloc((size_t)N * sizeof(int));
  int*   srcs   = (int*)alloc((size_t)E * sizeof(int));

  // CSR build (shared by both layers)
  k_zero_ints<<<dim3(80), dim3(256), 0, stream>>>(counts, N);
  k_hist<<<dim3(512), dim3(256), 0, stream>>>(dstp, E, counts);
  k_scan<<<dim3(1), dim3(64), 0, stream>>>(counts, starts, cursor, N);
  k_fill<<<dim3(512), dim3(256), 0, stream>>>(srcp, dstp, E, cursor, srcs);

  // prep
  k_prep_xh<<<dim3(1024), dim3(256), 0, stream>>>(x, bufX, N, Mpad);
  k_transpose_w<<<dim3(24, 24), dim3(256), 0, stream>>>(W1, Wt1);
  k_transpose_w<<<dim3(24, 24), dim3(256), 0, stream>>>(W2, Wt2);

  // layer 1: h1 = x@W1 ; attention ; out1 = elu(agg + b1)  (out1 -> bufX, fp16, pad zeroed)
  k_gemm_f16<<<dim3(Mpad / 128, 6), dim3(256), 0, stream>>>(bufX, Wt1, bufH, N);
  k_al<8><<<dim3((N + 3) / 4), dim3(256), 0, stream>>>(bufH, as1, ad1, als1, ald1, N);
  k_aggregate<8, false><<<dim3(Mpad), dim3(256), 0, stream>>>(bufH, als1, ald1, starts, srcs, b1, bufX, N);

  // layer 2: h2 = out1@W2 ; attention ; d_out = agg + b2 (f32)
  k_gemm_f16<<<dim3(Mpad / 128, 6), dim3(256), 0, stream>>>(bufX, Wt2, bufH, N);
  k_al<1><<<dim3((N + 3) / 4), dim3(256), 0, stream>>>(bufH, as2, ad2, als2, ald2, N);
  k_aggregate<1, true><<<dim3(N), dim3(256), 0, stream>>>(bufH, als2, ald2, starts, srcs, b2, d_out, N);
}

// Round 2
// 360.669 us; speedup vs baseline: 1.4064x; 1.4064x over previous
//
#include <hip/hip_runtime.h>
#include <cstdint>
#include <cstddef>

typedef _Float16 f16;
typedef _Float16 f16x4 __attribute__((ext_vector_type(4)));
typedef _Float16 f16x8 __attribute__((ext_vector_type(8)));
typedef float f32x4 __attribute__((ext_vector_type(4)));

#define LRELU_SLOPE 0.2f

// ---------------- prep: x (f32) -> x_h (f16), padded rows zeroed ----------------
__global__ __launch_bounds__(256) void k_prep_xh(const float* __restrict__ x,
                                                 f16* __restrict__ xh,
                                                 int nvalid, int npad) {
  int total = npad * 192;  // 768/4 float4-chunks per row
  for (int idx = blockIdx.x * blockDim.x + threadIdx.x; idx < total;
       idx += gridDim.x * blockDim.x) {
    int row = idx / 192;
    f16x4 o;
    if (row < nvalid) {
      const float4 v = *(const float4*)(x + (size_t)idx * 4);
      o[0] = (f16)v.x; o[1] = (f16)v.y; o[2] = (f16)v.z; o[3] = (f16)v.w;
    } else {
      o[0] = (f16)0.f; o[1] = (f16)0.f; o[2] = (f16)0.f; o[3] = (f16)0.f;
    }
    *(f16x4*)(xh + (size_t)idx * 4) = o;
  }
}

// ---------------- W [768][768] f32 -> Wt [n][k] f16 (transposed) ----------------
__global__ __launch_bounds__(256) void k_transpose_w(const float* __restrict__ W,
                                                     f16* __restrict__ Wt) {
  __shared__ float tile[32][33];
  int bn = blockIdx.x * 32;   // output-row block (n)
  int bk = blockIdx.y * 32;   // input-row block (k)
  int tx = threadIdx.x & 31, ty = threadIdx.x >> 5;  // ty 0..7
  #pragma unroll
  for (int r = ty; r < 32; r += 8)
    tile[r][tx] = W[(size_t)(bk + r) * 768 + bn + tx];
  __syncthreads();
  #pragma unroll
  for (int r = ty; r < 32; r += 8)
    Wt[(size_t)(bn + r) * 768 + bk + tx] = (f16)tile[tx][r];
}

// ---------------- CSR build ----------------
__global__ void k_zero_ints(int* __restrict__ p, int n) {
  for (int i = blockIdx.x * blockDim.x + threadIdx.x; i < n;
       i += gridDim.x * blockDim.x) p[i] = 0;
}

__global__ void k_hist(const int* __restrict__ dst, int E, int* __restrict__ counts) {
  for (int e = blockIdx.x * blockDim.x + threadIdx.x; e < E;
       e += gridDim.x * blockDim.x) atomicAdd(&counts[dst[e]], 1);
}

// single-block 1024-thread exclusive scan (replaces 156us serial single-wave scan)
__global__ __launch_bounds__(1024) void k_scan_block(const int* __restrict__ counts,
                                                     int* __restrict__ starts,
                                                     int* __restrict__ cursor, int n) {
  const int t = threadIdx.x;
  const int nthr = 1024;
  const int chunk = (n + nthr - 1) / nthr;
  const int base = t * chunk;
  int tsum = 0;
  for (int i = 0; i < chunk; i++) {
    int idx = base + i;
    if (idx < n) tsum += counts[idx];
  }
  // wave-level inclusive scan of per-thread sums
  int lane = t & 63, wv = t >> 6;
  int s = tsum;
  #pragma unroll
  for (int off = 1; off < 64; off <<= 1) {
    int tmp = __shfl_up(s, off);
    if (lane >= off) s += tmp;
  }
  __shared__ int wsum[16];
  if (lane == 63) wsum[wv] = s;
  __syncthreads();
  int woff = 0;
  for (int w = 0; w < wv; w++) woff += wsum[w];
  int run = woff + s - tsum;  // exclusive prefix for this thread's chunk
  for (int i = 0; i < chunk; i++) {
    int idx = base + i;
    if (idx < n) {
      starts[idx] = run;
      cursor[idx] = run;
      run += counts[idx];
    }
  }
  if (t == nthr - 1) starts[n] = run;  // thread covers through >= n, run == total
}

__global__ void k_fill(const int* __restrict__ src, const int* __restrict__ dst, int E,
                       int* __restrict__ cursor, int* __restrict__ src_sorted) {
  for (int e = blockIdx.x * blockDim.x + threadIdx.x; e < E;
       e += gridDim.x * blockDim.x) {
    int slot = atomicAdd(&cursor[dst[e]], 1);
    src_sorted[slot] = src[e];
  }
}

// ---------------- fp16 MFMA GEMM: C[M][768] = A[Mpad][768] * B(=Wt^T)[768][768] ----------------
__global__ __launch_bounds__(256) void k_gemm_f16(const f16* __restrict__ A,
                                                  const f16* __restrict__ Bt,
                                                  f16* __restrict__ C, int Mvalid) {
  __shared__ __align__(16) f16 As[4][128][8];
  __shared__ __align__(16) f16 Bs[4][128][8];
  const int K = 768;
  const int tid = threadIdx.x;
  const int bm = blockIdx.x * 128;
  const int bn = blockIdx.y * 128;
  const int lane = tid & 63;
  const int wave = tid >> 6;
  const int wr = (wave >> 1) * 64;
  const int wc = (wave & 1) * 64;
  const int ar = tid >> 2;
  const int ak = tid & 3;
  const f16* Ap = A + (size_t)(bm + ar) * K + ak * 8;
  const f16* Bp = Bt + (size_t)(bn + ar) * K + ak * 8;

  f32x4 acc[4][4];
  const f32x4 vzero = {0.f, 0.f, 0.f, 0.f};
  #pragma unroll
  for (int i = 0; i < 4; i++)
    #pragma unroll
    for (int j = 0; j < 4; j++) acc[i][j] = vzero;

  const int fr = lane & 15;
  const int fq = lane >> 4;

  for (int k0 = 0; k0 < K; k0 += 32) {
    *(f16x8*)(&As[ak][ar][0])      = *(const f16x8*)(Ap + k0);
    *(f16x8*)(&As[ak][ar + 64][0]) = *(const f16x8*)(Ap + (size_t)64 * K + k0);
    *(f16x8*)(&Bs[ak][ar][0])      = *(const f16x8*)(Bp + k0);
    *(f16x8*)(&Bs[ak][ar + 64][0]) = *(const f16x8*)(Bp + (size_t)64 * K + k0);
    __syncthreads();
    f16x8 af[4], bf[4];
    #pragma unroll
    for (int i = 0; i < 4; i++) af[i] = *(const f16x8*)(&As[fq][wr + i * 16 + fr][0]);
    #pragma unroll
    for (int j = 0; j < 4; j++) bf[j] = *(const f16x8*)(&Bs[fq][wc + j * 16 + fr][0]);
    #pragma unroll
    for (int i = 0; i < 4; i++)
      #pragma unroll
      for (int j = 0; j < 4; j++)
        acc[i][j] = __builtin_amdgcn_mfma_f32_16x16x32_f16(af[i], bf[j], acc[i][j], 0, 0, 0);
    __syncthreads();
  }

  #pragma unroll
  for (int i = 0; i < 4; i++) {
    #pragma unroll
    for (int j = 0; j < 4; j++) {
      int col = bn + wc + j * 16 + fr;
      #pragma unroll
      for (int r = 0; r < 4; r++) {
        int row = bm + wr + i * 16 + fq * 4 + r;
        if (row < Mvalid) C[(size_t)row * 768 + col] = (f16)acc[i][j][r];
      }
    }
  }
}

// ---------------- attention logits: al[n][h] = sum_c h[n][h*C+c]*a[h][c] ----------------
template <int H>
__global__ __launch_bounds__(256) void k_al(const f16* __restrict__ h,
                                            const float* __restrict__ a_src,
                                            const float* __restrict__ a_dst,
                                            float* __restrict__ als,
                                            float* __restrict__ ald, int N) {
  int node = blockIdx.x * 4 + (threadIdx.x >> 6);
  int lane = threadIdx.x & 63;
  if (node >= N) return;
  const f16x4* hp = (const f16x4*)(h + (size_t)node * 768 + lane * 12);
  float ss = 0.f, sd = 0.f;
  int cbase = lane * 12;
  #pragma unroll
  for (int q = 0; q < 3; q++) {
    f16x4 hv = hp[q];
    #pragma unroll
    for (int j = 0; j < 4; j++) {
      int c = cbase + q * 4 + j;
      float v = (float)hv[j];
      ss += v * a_src[c];
      sd += v * a_dst[c];
    }
  }
  const int red = (H == 8) ? 8 : 64;
  #pragma unroll
  for (int off = 1; off < red; off <<= 1) {
    ss += __shfl_xor(ss, off);
    sd += __shfl_xor(sd, off);
  }
  if (H == 8) {
    if ((lane & 7) == 0) {
      als[(size_t)node * 8 + (lane >> 3)] = ss;
      ald[(size_t)node * 8 + (lane >> 3)] = sd;
    }
  } else {
    if (lane == 0) { als[node] = ss; ald[node] = sd; }
  }
}

// ---------------- fused segment softmax + aggregation + bias (+ELU) ----------------
// 192 threads: thread t owns channels [4t..4t+3] (f16x4 gather loads).
// No segment-max (logits bounded, exp() safe in fp32); single fused pass computes
// exp values + running z; normalization division hoisted to the epilogue.
template <int H, bool FINAL>
__global__ __launch_bounds__(192) void k_aggregate(
    const f16* __restrict__ h, const float* __restrict__ als,
    const float* __restrict__ ald, const int* __restrict__ starts,
    const int* __restrict__ src_sorted, const float* __restrict__ bias,
    void* __restrict__ outv, int nvalid) {
  const int n = blockIdx.x;
  const int t = threadIdx.x;
  if (n >= nvalid) return;
  __shared__ float s_ex[256 * H];
  __shared__ int s_src[256];
  __shared__ float s_zp[3][H];  // per-wave per-head z partials
  const int start = starts[n];
  const int deg = starts[n + 1] - start;
  const int lane = t & 63, wv = t >> 6;
  const int hA = (H == 8) ? (t & 7) : 0;      // phase-A head (fixed per thread; 192%8==0)
  const int myh = (H == 8) ? (t / 24) : 0;    // phase-B head for channels 4t..4t+3
  const float ald_A = ald[(size_t)n * H + hA];

  float zpart = 0.f;
  float4 acc = {0.f, 0.f, 0.f, 0.f};

  for (int cb = 0; cb < deg; cb += 256) {
    const int cnt = min(256, deg - cb);
    // phase A: exp(leaky_relu(logit)) for all (edge, head); accumulate z partials
    for (int idx = t; idx < cnt * H; idx += 192) {
      const int e = (H == 8) ? (idx >> 3) : idx;
      const int s = src_sorted[start + cb + e];
      if (H == 1 || (idx & 7) == 0) s_src[e] = s;
      float v = als[(size_t)s * H + hA] + ald_A;
      v = v > 0.f ? v : LRELU_SLOPE * v;
      const float ex = __expf(v);
      s_ex[idx] = ex;
      zpart += ex;
    }
    __syncthreads();
    // phase B: unnormalized weighted gather
    for (int e = 0; e < cnt; e++) {
      const f16x4 hv = *(const f16x4*)(h + (size_t)s_src[e] * 768 + 4 * t);
      const float a = s_ex[e * H + myh];
      acc.x += a * (float)hv[0];
      acc.y += a * (float)hv[1];
      acc.z += a * (float)hv[2];
      acc.w += a * (float)hv[3];
    }
    __syncthreads();
  }

  // reduce z partials: threads sharing a head within a wave, then across 3 waves
  if (H == 8) {
    #pragma unroll
    for (int off = 8; off < 64; off <<= 1) zpart += __shfl_xor(zpart, off);
    if (lane < 8) s_zp[wv][lane] = zpart;
  } else {
    #pragma unroll
    for (int off = 1; off < 64; off <<= 1) zpart += __shfl_xor(zpart, off);
    if (lane == 0) s_zp[wv][0] = zpart;
  }
  __syncthreads();
  const float z = s_zp[0][myh] + s_zp[1][myh] + s_zp[2][myh];
  const float inv = 1.f / (z + 1e-16f);

  const float4 bv = *(const float4*)(bias + 4 * t);
  float v0 = acc.x * inv + bv.x;
  float v1 = acc.y * inv + bv.y;
  float v2 = acc.z * inv + bv.z;
  float v3 = acc.w * inv + bv.w;
  if (!FINAL) {
    v0 = v0 > 0.f ? v0 : expm1f(v0);
    v1 = v1 > 0.f ? v1 : expm1f(v1);
    v2 = v2 > 0.f ? v2 : expm1f(v2);
    v3 = v3 > 0.f ? v3 : expm1f(v3);
    f16x4 o;
    o[0] = (f16)v0; o[1] = (f16)v1; o[2] = (f16)v2; o[3] = (f16)v3;
    *(f16x4*)((f16*)outv + (size_t)n * 768 + 4 * t) = o;
  } else {
    float4 o = {v0, v1, v2, v3};
    *(float4*)((float*)outv + (size_t)n * 768 + 4 * t) = o;
  }
}

// ---------------- launcher ----------------
extern "C" void kernel_launch(void* const* d_in, const int* in_sizes, int n_in,
                              void* d_out, int out_size, void* d_ws, size_t ws_size,
                              hipStream_t stream) {
  const float* x   = (const float*)d_in[0];
  const int*   ei  = (const int*)d_in[1];
  const float* W1  = (const float*)d_in[2];
  const float* as1 = (const float*)d_in[3];
  const float* ad1 = (const float*)d_in[4];
  const float* b1  = (const float*)d_in[5];
  const float* W2  = (const float*)d_in[6];
  const float* as2 = (const float*)d_in[7];
  const float* ad2 = (const float*)d_in[8];
  const float* b2  = (const float*)d_in[9];

  const int N = in_sizes[0] / 768;
  const int E = in_sizes[1] / 2;
  const int Mpad = (N + 127) & ~127;
  const int* srcp = ei;
  const int* dstp = ei + E;

  char* p = (char*)d_ws;
  auto alloc = [&](size_t b) { char* r = p; p += (b + 255) & ~(size_t)255; return r; };
  f16*   bufX   = (f16*)alloc((size_t)Mpad * 768 * sizeof(f16));  // x_h, then out1
  f16*   bufH   = (f16*)alloc((size_t)Mpad * 768 * sizeof(f16));  // h1, then h2
  f16*   Wt1    = (f16*)alloc((size_t)768 * 768 * sizeof(f16));
  f16*   Wt2    = (f16*)alloc((size_t)768 * 768 * sizeof(f16));
  float* als1   = (float*)alloc((size_t)N * 8 * sizeof(float));
  float* ald1   = (float*)alloc((size_t)N * 8 * sizeof(float));
  float* als2   = (float*)alloc((size_t)N * sizeof(float));
  float* ald2   = (float*)alloc((size_t)N * sizeof(float));
  int*   counts = (int*)alloc((size_t)N * sizeof(int));
  int*   starts = (int*)alloc(((size_t)N + 1) * sizeof(int));
  int*   cursor = (int*)alloc((size_t)N * sizeof(int));
  int*   srcs   = (int*)alloc((size_t)E * sizeof(int));

  // CSR build (shared by both layers)
  k_zero_ints<<<dim3(80), dim3(256), 0, stream>>>(counts, N);
  k_hist<<<dim3(512), dim3(256), 0, stream>>>(dstp, E, counts);
  k_scan_block<<<dim3(1), dim3(1024), 0, stream>>>(counts, starts, cursor, N);
  k_fill<<<dim3(512), dim3(256), 0, stream>>>(srcp, dstp, E, cursor, srcs);

  // prep
  k_prep_xh<<<dim3(1024), dim3(256), 0, stream>>>(x, bufX, N, Mpad);
  k_transpose_w<<<dim3(24, 24), dim3(256), 0, stream>>>(W1, Wt1);
  k_transpose_w<<<dim3(24, 24), dim3(256), 0, stream>>>(W2, Wt2);

  // layer 1
  k_gemm_f16<<<dim3(Mpad / 128, 6), dim3(256), 0, stream>>>(bufX, Wt1, bufH, N);
  k_al<8><<<dim3((N + 3) / 4), dim3(256), 0, stream>>>(bufH, as1, ad1, als1, ald1, N);
  k_aggregate<8, false><<<dim3(N), dim3(192), 0, stream>>>(bufH, als1, ald1, starts, srcs, b1, bufX, N);

  // layer 2
  k_gemm_f16<<<dim3(Mpad / 128, 6), dim3(256), 0, stream>>>(bufX, Wt2, bufH, N);
  k_al<1><<<dim3((N + 3) / 4), dim3(256), 0, stream>>>(bufH, as2, ad2, als2, ald2, N);
  k_aggregate<1, true><<<dim3(N), dim3(192), 0, stream>>>(bufH, als2, ald2, starts, srcs, b2, d_out, N);
}